// Round 3
// baseline (32.280 us; speedup 1.0000x reference)
//
#include <hip/hip_runtime.h>

#define NK 8
#define NR 32
#define NF 16
#define NB 32768
#define RSTR 64  // floats per (k,r) record: [0:16)=A, [16:32)=B, [32:48)=W, [48]=C, [49]=bias, pad to 256B

__device__ __forceinline__ float fexp2(float v) {
#if __has_builtin(__builtin_amdgcn_exp2f)
    return __builtin_amdgcn_exp2f(v);
#else
    return __expf(v * 0.6931471805599453f);
#endif
}

// Fold params: exp(-(x-mu)^2/(2s^2)) = exp2(A x^2 + B x + Cf), A=-log2e/(2s^2), B=-2A mu, Cf=A mu^2.
// One thread per (k,r,f); C = sum_f Cf via 16-lane-group shuffle reduce.
__global__ void hfnn_prep(const float* __restrict__ mu,
                          const float* __restrict__ sg,
                          const float* __restrict__ w3,
                          float* __restrict__ pp) {
    int t = blockIdx.x * blockDim.x + threadIdx.x;
    if (t >= NK * NR * NF) return;
    int kr = t >> 4, f = t & 15;
    float muv = mu[t];
    float sv  = sg[t];
    float A   = -1.4426950408889634f * (0.5f / (sv * sv));
    float B   = -2.0f * muv * A;
    float Cf  = A * muv * muv;
    Cf += __shfl_xor(Cf, 1, 16);
    Cf += __shfl_xor(Cf, 2, 16);
    Cf += __shfl_xor(Cf, 4, 16);
    Cf += __shfl_xor(Cf, 8, 16);
    float* rec = pp + (size_t)kr * RSTR;
    rec[f]          = A;
    rec[NF + f]     = B;
    rec[2 * NF + f] = w3[kr * (NF + 1) + f];
    if (f == 0) { rec[48] = Cf; rec[49] = w3[kr * (NF + 1) + NF]; }
}

// Block = 512 = 8 waves; wave k <-> branch k, 64 batch elems per block.
// Params come through the SCALAR pipe (s_load into SGPRs, shared by the wave):
// every VALU op below uses at most one SGPR operand (the param), VGPRs for x/x2/accums.
__global__ __launch_bounds__(512, 4) void hfnn_main(
    const float* __restrict__ data, const float* __restrict__ pp,
    const float* __restrict__ w5,   const float* __restrict__ b5,
    float* __restrict__ out)
{
    __shared__ float tl[NK][64];

    const int lane = threadIdx.x & 63;
    const int k    = __builtin_amdgcn_readfirstlane((int)(threadIdx.x >> 6));
    const int b    = blockIdx.x * 64 + lane;

    const float* xp = data + ((size_t)k * NB + b) * NF;
    float x[NF];
#pragma unroll
    for (int i = 0; i < 4; ++i)
        reinterpret_cast<float4*>(x)[i] = reinterpret_cast<const float4*>(xp)[i];
    float x2[NF];
#pragma unroll
    for (int f = 0; f < NF; ++f) x2[f] = x[f] * x[f];

    const float* base = pp + (size_t)k * NR * RSTR;  // wave-uniform -> s_load path
    float num = 0.f, den = 0.f;

#pragma unroll 2
    for (int r = 0; r < NR; ++r) {
        const float* rec = base + r * RSTR;
        float sA = rec[48];      // C folded into exponent accumulator
        float cq = rec[49];      // bias folded into consequent accumulator
        float sB = 0.f;
#pragma unroll
        for (int f = 0; f < NF; ++f) {
            sA = fmaf(x2[f], rec[f],          sA);   // A_f * x^2
            sB = fmaf(x[f],  rec[NF + f],     sB);   // B_f * x
            cq = fmaf(x[f],  rec[2 * NF + f], cq);   // W_f * x
        }
        float e = fexp2(sA + sB);
        num = fmaf(e, cq, num);
        den += e;
    }

    tl[k][lane] = __fdividef(num, den);   // tsk[k][b]
    __syncthreads();

    if (threadIdx.x < 64) {               // wave 0: branch combine + 2-class softmax
        float l0 = b5[0], l1 = b5[1];
#pragma unroll
        for (int kk = 0; kk < NK; ++kk) {
            float t = tl[kk][lane];
            l0 = fmaf(t, w5[kk],      l0);
            l1 = fmaf(t, w5[NK + kk], l1);
        }
        float m  = fmaxf(l0, l1);
        float e0 = __expf(l0 - m);
        float e1 = __expf(l1 - m);
        float inv = __fdividef(1.f, e0 + e1);
        *reinterpret_cast<float2*>(out + (size_t)(blockIdx.x * 64 + lane) * 2) =
            make_float2(e0 * inv, e1 * inv);
    }
}

extern "C" void kernel_launch(void* const* d_in, const int* in_sizes, int n_in,
                              void* d_out, int out_size, void* d_ws, size_t ws_size,
                              hipStream_t stream) {
    const float* data = (const float*)d_in[0];
    const float* mu   = (const float*)d_in[1];
    const float* sg   = (const float*)d_in[2];
    const float* w3   = (const float*)d_in[3];
    const float* w5   = (const float*)d_in[4];
    const float* b5   = (const float*)d_in[5];
    float* out = (float*)d_out;
    float* pp  = (float*)d_ws;   // 8*32*64*4 = 64 KB

    hfnn_prep<<<(NK * NR * NF + 255) / 256, 256, 0, stream>>>(mu, sg, w3, pp);
    hfnn_main<<<NB / 64, 512, 0, stream>>>(data, pp, w5, b5, out);
}

// Round 4
// 15.142 us; speedup vs baseline: 2.1318x; 2.1318x over previous
//
#include <hip/hip_runtime.h>

#define NK 8
#define NR 32
#define NF 16
#define NB 32768
#define LOG2E 1.4426950408889634f

typedef _Float16 f16x8 __attribute__((ext_vector_type(8)));
typedef float    f32x4 __attribute__((ext_vector_type(4)));

// PF: [k][t][lane][8] f16 — A-fragments for mfma_f32_16x16x32_f16.
//   row = 16t + (lane&15), kappa = (lane>>4)*8 + j
//   row<32  (rule r=row):    kappa<16 -> A_f = -log2e/(2 sigma^2)   (f=kappa)
//                            kappa>=16 -> B_f = -2*A_f*mu            (f=kappa-16)
//   row>=32 (rule r=row-32): kappa<16 -> 0 ; kappa>=16 -> W_f
// CB: [k][64] f32 — accumulator init: row<32 -> C_r = sum_f A_f mu^2 ; row>=32 -> bias_r
__global__ void hfnn_prep(const float* __restrict__ mu,
                          const float* __restrict__ sg,
                          const float* __restrict__ w3,
                          _Float16* __restrict__ PF,
                          float* __restrict__ CB) {
    int tid = blockIdx.x * blockDim.x + threadIdx.x;
    if (tid < NK * 4 * 64) {
        int k = tid >> 8, t = (tid >> 6) & 3, l = tid & 63;
        int row = 16 * t + (l & 15);
        int k0  = (l >> 4) * 8;
        _Float16* dst = PF + (size_t)tid * 8;
        for (int j = 0; j < 8; ++j) {
            int kp = k0 + j;
            float val;
            if (row < 32) {
                int f = (kp < 16) ? kp : (kp - 16);
                float s = sg[(k * NR + row) * NF + f];
                float a = -LOG2E * 0.5f / (s * s);
                val = (kp < 16) ? a : (-2.0f * a * mu[(k * NR + row) * NF + f]);
            } else {
                int r = row - 32;
                val = (kp < 16) ? 0.0f : w3[(k * NR + r) * (NF + 1) + (kp - 16)];
            }
            dst[j] = (_Float16)val;
        }
    }
    if (tid < NK * 64) {
        int k = tid >> 6, row = tid & 63;
        float v;
        if (row < 32) {
            float c = 0.f;
            for (int f = 0; f < NF; ++f) {
                float s = sg[(k * NR + row) * NF + f];
                float m = mu[(k * NR + row) * NF + f];
                c += (-LOG2E * 0.5f / (s * s)) * m * m;
            }
            v = c;
        } else {
            v = w3[(k * NR + (row - 32)) * (NF + 1) + NF];
        }
        CB[tid] = v;
    }
}

// Block = 512 = 8 waves; wave k <-> branch k, 64 batch elems per block (4 MFMA tiles of 16).
// Params live in 16 persistent VGPRs (A-frags); x streams HBM->VGPR coalesced.
__global__ __launch_bounds__(512, 4) void hfnn_main(
    const float* __restrict__ data, const _Float16* __restrict__ PF,
    const float* __restrict__ CB,   const float* __restrict__ w5,
    const float* __restrict__ b5,   float* __restrict__ out)
{
    __shared__ float tl[NK][64];
    const int lane = threadIdx.x & 63;
    const int k    = threadIdx.x >> 6;
    const int g    = lane >> 4;       // k-group (0..3)
    const int col  = lane & 15;       // batch col within tile / output col

    f16x8 afrag[4];
    f32x4 cbv[4];
#pragma unroll
    for (int t = 0; t < 4; ++t) {
        afrag[t] = *reinterpret_cast<const f16x8*>(PF + (((size_t)k * 4 + t) * 64 + lane) * 8);
        cbv[t]   = *reinterpret_cast<const f32x4*>(CB + k * 64 + 16 * t + g * 4);
    }

    const int bbase = blockIdx.x * 64;
#pragma unroll
    for (int c = 0; c < 4; ++c) {
        const int b = bbase + c * 16 + col;
        const float* xp = data + ((size_t)k * NB + b) * NF + (g & 1) * 8;
        float4 v0 = reinterpret_cast<const float4*>(xp)[0];
        float4 v1 = reinterpret_cast<const float4*>(xp)[1];
        if (g < 2) {   // k-groups 0,1 supply the x^2 half (kappa 0..15)
            v0.x *= v0.x; v0.y *= v0.y; v0.z *= v0.z; v0.w *= v0.w;
            v1.x *= v1.x; v1.y *= v1.y; v1.z *= v1.z; v1.w *= v1.w;
        }
        f16x8 bf;
        bf[0] = (_Float16)v0.x; bf[1] = (_Float16)v0.y;
        bf[2] = (_Float16)v0.z; bf[3] = (_Float16)v0.w;
        bf[4] = (_Float16)v1.x; bf[5] = (_Float16)v1.y;
        bf[6] = (_Float16)v1.z; bf[7] = (_Float16)v1.w;

        f32x4 a0 = __builtin_amdgcn_mfma_f32_16x16x32_f16(afrag[0], bf, cbv[0], 0, 0, 0);
        f32x4 a1 = __builtin_amdgcn_mfma_f32_16x16x32_f16(afrag[1], bf, cbv[1], 0, 0, 0);
        f32x4 a2 = __builtin_amdgcn_mfma_f32_16x16x32_f16(afrag[2], bf, cbv[2], 0, 0, 0);
        f32x4 a3 = __builtin_amdgcn_mfma_f32_16x16x32_f16(afrag[3], bf, cbv[3], 0, 0, 0);

        // lane covers rules {g*4+j} (a0/a2 pair) and {16+g*4+j} (a1/a3 pair)
        float num = 0.f, den = 0.f;
#pragma unroll
        for (int j = 0; j < 4; ++j) {
            float e0 = __builtin_amdgcn_exp2f(a0[j]);
            float e1 = __builtin_amdgcn_exp2f(a1[j]);
            den += e0 + e1;
            num = fmaf(e0, a2[j], num);
            num = fmaf(e1, a3[j], num);
        }
        num += __shfl_xor(num, 16);
        den += __shfl_xor(den, 16);
        num += __shfl_xor(num, 32);
        den += __shfl_xor(den, 32);
        if (lane < 16) tl[k][c * 16 + lane] = __fdividef(num, den);
    }
    __syncthreads();

    if (threadIdx.x < 64) {           // wave 0: branch combine + 2-class softmax
        float l0 = b5[0], l1 = b5[1];
#pragma unroll
        for (int kk = 0; kk < NK; ++kk) {
            float t = tl[kk][lane];
            l0 = fmaf(t, w5[kk],      l0);
            l1 = fmaf(t, w5[NK + kk], l1);
        }
        float m  = fmaxf(l0, l1);
        float e0 = __expf(l0 - m);
        float e1 = __expf(l1 - m);
        float inv = __fdividef(1.f, e0 + e1);
        *reinterpret_cast<float2*>(out + (size_t)(blockIdx.x * 64 + lane) * 2) =
            make_float2(e0 * inv, e1 * inv);
    }
}

extern "C" void kernel_launch(void* const* d_in, const int* in_sizes, int n_in,
                              void* d_out, int out_size, void* d_ws, size_t ws_size,
                              hipStream_t stream) {
    const float* data = (const float*)d_in[0];
    const float* mu   = (const float*)d_in[1];
    const float* sg   = (const float*)d_in[2];
    const float* w3   = (const float*)d_in[3];
    const float* w5   = (const float*)d_in[4];
    const float* b5   = (const float*)d_in[5];
    float* out = (float*)d_out;

    _Float16* PF = (_Float16*)d_ws;                       // 8*4*64*8 f16 = 32 KB
    float*    CB = (float*)((char*)d_ws + 32768);         // 8*64 f32 = 2 KB

    hfnn_prep<<<8, 256, 0, stream>>>(mu, sg, w3, PF, CB);
    hfnn_main<<<NB / 64, 512, 0, stream>>>(data, PF, CB, w5, b5, out);
}